// Round 3
// baseline (474.481 us; speedup 1.0000x reference)
//
#include <hip/hip_runtime.h>
#include <hip/hip_cooperative_groups.h>

namespace cg = cooperative_groups;

#define U 256       // unknown node count
#define NN 1024     // total nodes
#define NROWS 32768 // B*T rows
#define LCAP 32     // capacity of "less" (earlier-unknown-neighbor) list per node
#define DUMMY 256   // padded index -> zero row of Ms

typedef __bf16 bf16_t;
typedef __bf16 bf16x4 __attribute__((ext_vector_type(4)));
typedef __bf16 bf16x8 __attribute__((ext_vector_type(8)));
typedef float f32x4 __attribute__((ext_vector_type(4)));
typedef unsigned short u16;
typedef unsigned short u16x8 __attribute__((ext_vector_type(8)));
typedef short s16x4 __attribute__((ext_vector_type(4)));

// ---------------------------------------------------------------------------
// Fused setup: struct -> levels -> mbuild -> wbuild in ONE cooperative kernel.
// grid 256 x 256 thr, ~58 KB LDS -> 1 block/CU, co-residency guaranteed.
// Phases separated by grid.sync(); all numerics identical to the 4-kernel
// version (same op order per phase).
// ---------------------------------------------------------------------------
__global__ __launch_bounds__(256) void k_setup(const float* __restrict__ A,
    const int* __restrict__ unknown, const float* __restrict__ maskp,
    float* __restrict__ invDeg, float* __restrict__ coef,
    int* __restrict__ lessCnt, u16* __restrict__ lessIdx,
    int* __restrict__ uflag, short* __restrict__ pmap,
    int* __restrict__ order, int* __restrict__ levelStart, int* __restrict__ nLev,
    float* __restrict__ MT, bf16_t* __restrict__ Wb, float* __restrict__ bvec)
{
    cg::grid_group grid = cg::this_grid();
    __shared__ int sunk[U];
    __shared__ float sdeg;
    __shared__ int scnt, sge;
    __shared__ u16 sIdx[U * LCAP];      // shared by phases B and C (same content)
    __shared__ int slvl[U];
    __shared__ int scL[U];
    __shared__ int hist[U];
    __shared__ int changed;
    __shared__ float Ms[(U + 1) * 32];  // row U = zeros (dummy target)
    __shared__ float sInv[U];
    __shared__ u16 sOrd[U];
    __shared__ unsigned char sCnt[U];
    __shared__ int sLs[U + 1];
    __shared__ int nnz;
    __shared__ int cs[64];
    __shared__ float vsv[64];
    __shared__ float scf[U];

    int t = threadIdx.x, k = blockIdx.x;

    // ---- Phase A: per-unknown-node struct (block k -> node k) ----
    sunk[t] = unknown[t];
    if (t == 0) { sdeg = 0.f; scnt = 0; sge = 0; }
    __syncthreads();
    {
        int uk = sunk[k];
        float dsum = 0.f;
        for (int i = 0; i < NN / 256; ++i) {
            int n = t + 256 * i;
            float a = A[(size_t)uk * NN + n];
            if (a != 0.f) {
                dsum += a;
                int lo = 0, hi = U;
                while (lo < hi) { int mid = (lo + hi) >> 1; if (sunk[mid] < n) lo = mid + 1; else hi = mid; }
                if (lo < U && sunk[lo] == n) {
                    if (lo < k) {
                        int id = atomicAdd(&scnt, 1);
                        if (id < LCAP) lessIdx[k * LCAP + id] = (u16)lo;
                    } else {
                        atomicAdd(&sge, 1);
                    }
                }
            }
        }
        atomicAdd(&sdeg, dsum);
        __syncthreads();
        int c0 = min(scnt, LCAP);
        if (t >= c0 && t < LCAP) lessIdx[k * LCAP + t] = DUMMY;   // pad
        if (t == 0) {
            float inv = 1.f / sdeg;
            invDeg[k] = inv;
            coef[k] = (float)sge * maskp[0] * inv;
            lessCnt[k] = c0;
        }
        if (k == 0) {
            for (int i = 0; i < NN / 256; ++i) { uflag[t + 256 * i] = 0; pmap[t + 256 * i] = -1; }
            __syncthreads();
            uflag[sunk[t]] = 1;
            pmap[sunk[t]] = (short)t;
        }
    }
    __threadfence();
    grid.sync();

    // ---- Phase B: topo levels (block 0 only) ----
    if (k == 0) {
        for (int i = t; i < U * LCAP / 2; i += 256) ((unsigned int*)sIdx)[i] = ((const unsigned int*)lessIdx)[i];
        scL[t] = lessCnt[t];
        slvl[t] = 0; hist[t] = 0;
        __syncthreads();
        for (int iter = 0; iter < U; ++iter) {
            if (t == 0) changed = 0;
            __syncthreads();
            int c = scL[t], nl = 0;
            for (int i = 0; i < c; ++i) nl = max(nl, slvl[sIdx[t * LCAP + i]] + 1);
            if (nl > slvl[t]) { slvl[t] = nl; changed = 1; }
            __syncthreads();
            if (!changed) break;   // uniform
        }
        int L = slvl[t];
        atomicAdd(&hist[L], 1);
        __syncthreads();
        if (t == 0) {
            int acc = 0, lastl = 0;
            for (int l = 0; l < U; ++l) {
                int h = hist[l];
                hist[l] = acc;          // hist becomes start offset
                acc += h;
                if (h > 0) lastl = l;
            }
            nLev[0] = lastl + 1;
        }
        __syncthreads();
        levelStart[t] = hist[t];        // save starts BEFORE scatter clobbers
        if (t == 0) levelStart[U] = U;
        __syncthreads();
        int pos = atomicAdd(&hist[L], 1);
        order[pos] = t;
    }
    __threadfence();
    grid.sync();

    // ---- Phase C: M = (I - Ltilde)^-1, level-parallel (blocks 0..7) ----
    if (k < 8) {
        int g = t >> 5, c = t & 31;
        int col = k * 32 + c;
        for (int i = t; i < U * LCAP / 2; i += 256) ((unsigned int*)sIdx)[i] = ((const unsigned int*)lessIdx)[i];
        sInv[t] = invDeg[t];
        sOrd[t] = (u16)order[t];
        sCnt[t] = (unsigned char)lessCnt[t];
        sLs[t] = levelStart[t];
        if (t == 0) sLs[U] = levelStart[U];
        if (t < 32) Ms[U * 32 + t] = 0.f;
        int nlv = nLev[0];
        __syncthreads();
        for (int lev = 0; lev < nlv; ++lev) {
            int s = sLs[lev], e = sLs[lev + 1];
            for (int base = s + g; base < e; base += 8) {
                int nd = sOrd[base];
                int cnt = sCnt[nd];
                const u16* ip = &sIdx[nd * LCAP];
                float sum = 0.f;
                for (int b = 0; b < cnt; b += 8) {
                    u16x8 jv = *(const u16x8*)(ip + b);   // one ds_read_b128
                    float v0 = Ms[jv[0] * 32 + c];
                    float v1 = Ms[jv[1] * 32 + c];
                    float v2 = Ms[jv[2] * 32 + c];
                    float v3 = Ms[jv[3] * 32 + c];
                    float v4 = Ms[jv[4] * 32 + c];
                    float v5 = Ms[jv[5] * 32 + c];
                    float v6 = Ms[jv[6] * 32 + c];
                    float v7 = Ms[jv[7] * 32 + c];
                    sum += ((v0 + v1) + (v2 + v3)) + ((v4 + v5) + (v6 + v7));
                }
                float m = (nd == col ? 1.f : 0.f) + sInv[nd] * sum;
                Ms[nd * 32 + c] = m;
                MT[(size_t)col * U + nd] = m;
            }
            __syncthreads();   // level boundary
        }
    }
    __threadfence();
    grid.sync();

    // ---- Phase D: W (bf16) + bvec; block b handles d = b, b+256, b+512, b+768 ----
    {
        int unk = sunk[t];              // still valid from phase A
        float inv = invDeg[t];
        for (int dd = 0; dd < 4; ++dd) {
            int d = k + 256 * dd;
            __syncthreads();            // protect cs/vsv reuse
            if (t == 0) nnz = 0;
            __syncthreads();
            int skip = uflag[d];        // block-uniform
            if (!skip) {
                float a = A[(size_t)unk * NN + d];
                if (a != 0.f) {
                    int id = atomicAdd(&nnz, 1);
                    if (id < 64) { cs[id] = t; vsv[id] = a * inv; }
                }
            }
            __syncthreads();
            if (skip) {
                Wb[(size_t)t * NN + d] = (bf16_t)0.f;
            } else {
                int n = min(nnz, 64);
                float s = 0.f;
                for (int i = 0; i < n; ++i)
                    s += MT[(size_t)cs[i] * U + t] * vsv[i];   // coalesced over t
                Wb[(size_t)t * NN + d] = (bf16_t)s;
            }
        }
        if (k == 0) {
            __syncthreads();
            scf[t] = coef[t];
            __syncthreads();
            float s = 0.f;
            #pragma unroll 8
            for (int c = 0; c < U; ++c) s += MT[(size_t)c * U + t] * scf[c];
            bvec[t] = s;
        }
    }
}

// ---------------------------------------------------------------------------
// K3 v3: GEMM out[:,unknown] = x*W^T + b. RT=32 (grid 1024 -> 3 blocks/CU via
// __launch_bounds__(256,3)) + register-prefetch pipeline from v2: chunk t+1's
// global loads issued right after the post-store barrier, flying under chunk
// t's ds_read+MFMA. Wb L2 re-fetch doubles vs RT=64 but never hits HBM
// (round-1/2 FETCH_SIZE == x-bytes exactly). Numerics identical to round 1.
// ---------------------------------------------------------------------------
#define RT 32
#define BK 64
#define LDX 72      // 64 + 8 bf16 pad: 2-way-max LDS banks
#define URS 257     // Ures row stride (f32)

__global__ __launch_bounds__(256, 3) void k_main(const float* __restrict__ x,
    const short* __restrict__ pmap, const bf16_t* __restrict__ Wb,
    const float* __restrict__ bvec, float* __restrict__ out)
{
    __shared__ __align__(16) char smem[41472];  // max(Xl 4608 + Vl 36864, Ures 32896)
    __shared__ float sb[U];
    __shared__ short spm[NN];
    bf16_t* Xl = (bf16_t*)smem;
    bf16_t* Vl = (bf16_t*)(smem + 4608);
    float* Ures = (float*)smem;
    int t = threadIdx.x;
    int w = t >> 6, l = t & 63;
    int m = l & 15, q = l >> 4;
    size_t row0 = (size_t)blockIdx.x * RT;
    sb[t] = bvec[t];
    #pragma unroll
    for (int j = 0; j < 4; ++j) spm[t + 256 * j] = pmap[t + 256 * j];
    f32x4 acc[2][4] = {};
    int uv = t >> 3, du = (t & 7) * 8;

    // register prefetch buffers
    float4 xr[2];
    bf16x8 vr[8];

#define LOADC(DB) do { \
    _Pragma("unroll") \
    for (int ii = 0; ii < 2; ++ii) { \
        int flat = t + ii * 256; \
        int r = flat >> 4, c4 = (flat & 15) * 4; \
        xr[ii] = *(const float4*)(x + (row0 + r) * NN + (DB) + c4); \
    } \
    _Pragma("unroll") \
    for (int i = 0; i < 8; ++i) \
        vr[i] = *(const bf16x8*)(Wb + (size_t)(uv + 32 * i) * NN + (DB) + du); \
} while (0)

    LOADC(0);
    for (int db = 0; db < NN; db += BK) {
        __syncthreads();   // prior compute's LDS reads done (covers sb/spm on iter 0)
        // stage X chunk [32r x 64d] fp32 -> bf16 LDS
        #pragma unroll
        for (int ii = 0; ii < 2; ++ii) {
            int flat = t + ii * 256;
            int r = flat >> 4, c4 = (flat & 15) * 4;
            float4 v = xr[ii];
            bf16x4 hv = { (bf16_t)v.x, (bf16_t)v.y, (bf16_t)v.z, (bf16_t)v.w };
            *(bf16x4*)(&Xl[r * LDX + c4]) = hv;
        }
        // stage V chunk [256u x 64d] bf16
        #pragma unroll
        for (int i = 0; i < 8; ++i)
            *(bf16x8*)(&Vl[(uv + 32 * i) * LDX + du]) = vr[i];
        __syncthreads();   // nothing in flight here -> implicit vmcnt(0) free
        if (db + BK < NN) LOADC(db + BK);   // prefetch flies under compute below
        #pragma unroll
        for (int s = 0; s < 2; ++s) {
            bf16x8 af[2];
            #pragma unroll
            for (int R = 0; R < 2; ++R)
                af[R] = *(bf16x8*)(&Xl[(R * 16 + m) * LDX + s * 32 + q * 8]);
            #pragma unroll
            for (int T = 0; T < 4; ++T) {
                bf16x8 bfr = *(bf16x8*)(&Vl[((w * 4 + T) * 16 + m) * LDX + s * 32 + q * 8]);
                #pragma unroll
                for (int R = 0; R < 2; ++R)
                    acc[R][T] = __builtin_amdgcn_mfma_f32_16x16x32_bf16(af[R], bfr, acc[R][T], 0, 0, 0);
            }
        }
    }
#undef LOADC
    __syncthreads();   // all Vl/Xl reads done before Ures overwrite
    // stage acc (+bias) into Ures[r][u] f32; C/D layout row=q*4+i, col=m
    #pragma unroll
    for (int R = 0; R < 2; ++R) {
        #pragma unroll
        for (int T = 0; T < 4; ++T) {
            int u = (w * 4 + T) * 16 + m;
            float bb = sb[u];
            #pragma unroll
            for (int i = 0; i < 4; ++i)
                Ures[(R * 16 + q * 4 + i) * URS + u] = acc[R][T][i] + bb;
        }
    }
    __syncthreads();
    // merged single-pass write: re-read x (L3-warm), substitute unknown cols
    s16x4 pm = *(const s16x4*)(&spm[t * 4]);
    #pragma unroll 4
    for (int i = 0; i < RT; ++i) {
        float4 v = *(const float4*)(x + (row0 + i) * NN + t * 4);
        if (pm[0] >= 0) v.x = Ures[i * URS + pm[0]];
        if (pm[1] >= 0) v.y = Ures[i * URS + pm[1]];
        if (pm[2] >= 0) v.z = Ures[i * URS + pm[2]];
        if (pm[3] >= 0) v.w = Ures[i * URS + pm[3]];
        *(float4*)(out + (row0 + i) * NN + t * 4) = v;
    }
}

// ---------------------------------------------------------------------------
extern "C" void kernel_launch(void* const* d_in, const int* in_sizes, int n_in,
                              void* d_out, int out_size, void* d_ws, size_t ws_size,
                              hipStream_t stream)
{
    const float* x       = (const float*)d_in[0];
    const float* A       = (const float*)d_in[1];
    const int*   unknown = (const int*)d_in[2];
    const float* maskp   = (const float*)d_in[3];
    float* out = (float*)d_out;

    char* ws = (char*)d_ws;
    float*  MT        = (float*)(ws + 0);        // 262144 B
    bf16_t* Wb        = (bf16_t*)(ws + 262144);  // 524288 B
    float*  invDeg    = (float*)(ws + 786432);
    float*  coef      = (float*)(ws + 787456);
    float*  bvec      = (float*)(ws + 788480);
    int*    lessCnt   = (int*)(ws + 789504);
    u16*    lessIdx   = (u16*)(ws + 790528);     // 16384 B
    int*    uflag     = (int*)(ws + 806912);     // 4096 B
    short*  pmap      = (short*)(ws + 811008);   // 2048 B
    int*    order     = (int*)(ws + 813056);     // 1024 B
    int*    levelStart= (int*)(ws + 814080);     // 1040 B
    int*    nLev      = (int*)(ws + 815120);     // 4 B

    void* cargs[15] = { (void*)&A, (void*)&unknown, (void*)&maskp, (void*)&invDeg,
                        (void*)&coef, (void*)&lessCnt, (void*)&lessIdx, (void*)&uflag,
                        (void*)&pmap, (void*)&order, (void*)&levelStart, (void*)&nLev,
                        (void*)&MT, (void*)&Wb, (void*)&bvec };
    hipLaunchCooperativeKernel((void*)k_setup, dim3(U), dim3(256), cargs, 0, stream);

    hipLaunchKernelGGL(k_main, dim3(NROWS / RT), dim3(256), 0, stream,
                       x, pmap, Wb, bvec, out);
}

// Round 4
// 334.211 us; speedup vs baseline: 1.4197x; 1.4197x over previous
//
#include <hip/hip_runtime.h>

#define U 256       // unknown node count
#define NN 1024     // total nodes
#define NROWS 32768 // B*T rows
#define LCAP 32     // capacity of "less" (earlier-unknown-neighbor) list per node
#define DUMMY 256   // padded index -> zero row of Ms

typedef __bf16 bf16_t;
typedef __bf16 bf16x4 __attribute__((ext_vector_type(4)));
typedef __bf16 bf16x8 __attribute__((ext_vector_type(8)));
typedef float f32x4 __attribute__((ext_vector_type(4)));
typedef unsigned short u16;
typedef unsigned short u16x8 __attribute__((ext_vector_type(8)));
typedef short s16x4 __attribute__((ext_vector_type(4)));

// ---------------------------------------------------------------------------
// K0: per unknown node k (one block each): deg, 1/deg, coef, less-list, AND
// the binary known-column weight row Vb[k][d] = (A[uk][d]!=0 && d not unknown)
// ? 1 : 0 (bf16-exact). Block 0 also builds pmap and zeroes bvec.
// The big GEMM needs ONLY Vb -> M/levels drop off its critical path.
// ---------------------------------------------------------------------------
__global__ __launch_bounds__(256) void k_struct(const float* __restrict__ A,
    const int* __restrict__ unknown, const float* __restrict__ maskp,
    float* __restrict__ invDeg, float* __restrict__ coef,
    int* __restrict__ lessCnt, u16* __restrict__ lessIdx,
    short* __restrict__ pmap, float* __restrict__ bvec, bf16_t* __restrict__ Vb)
{
    __shared__ int sunk[U];
    __shared__ float sdeg;
    __shared__ int scnt, sge;
    int t = threadIdx.x, k = blockIdx.x;
    sunk[t] = unknown[t];
    if (t == 0) { sdeg = 0.f; scnt = 0; sge = 0; }
    __syncthreads();
    int uk = sunk[k];
    float dsum = 0.f;
    for (int i = 0; i < NN / 256; ++i) {
        int n = t + 256 * i;
        float a = A[(size_t)uk * NN + n];
        int isU = 0;
        if (a != 0.f) {
            dsum += a;
            int lo = 0, hi = U;
            while (lo < hi) { int mid = (lo + hi) >> 1; if (sunk[mid] < n) lo = mid + 1; else hi = mid; }
            if (lo < U && sunk[lo] == n) {
                isU = 1;
                if (lo < k) {
                    int id = atomicAdd(&scnt, 1);
                    if (id < LCAP) lessIdx[k * LCAP + id] = (u16)lo;
                } else {
                    atomicAdd(&sge, 1);
                }
            }
        }
        // binary known-col weight (exact in bf16: A entries are 0/1)
        Vb[(size_t)k * NN + n] = (a != 0.f && !isU) ? (bf16_t)1.f : (bf16_t)0.f;
    }
    atomicAdd(&sdeg, dsum);
    __syncthreads();
    int c0 = min(scnt, LCAP);
    if (t >= c0 && t < LCAP) lessIdx[k * LCAP + t] = DUMMY;   // pad
    if (t == 0) {
        float inv = 1.f / sdeg;
        invDeg[k] = inv;
        coef[k] = (float)sge * maskp[0] * inv;
        lessCnt[k] = c0;
    }
    if (k == 0) {
        for (int i = 0; i < NN / 256; ++i) pmap[t + 256 * i] = -1;
        bvec[t] = 0.f;                      // accumulated by k_mbuild atomics
        __syncthreads();
        pmap[sunk[t]] = (short)t;
    }
}

// ---------------------------------------------------------------------------
// K1: levels (computed REDUNDANTLY per block -- 8 concurrent blocks, no extra
// kernel, no grid sync) + level-parallel forward substitution for
// M = (I - Ltilde)^-1. Writes M2[k][col] bf16 (row-major, stride U) for the
// GEMM2 B-operand, and atomically accumulates bvec = M * coef.
// ---------------------------------------------------------------------------
__global__ __launch_bounds__(256) void k_mbuild(const int* __restrict__ lessCnt,
    const u16* __restrict__ lessIdx, const float* __restrict__ invDeg,
    const float* __restrict__ coef, bf16_t* __restrict__ M2, float* __restrict__ bvec)
{
    __shared__ u16 sIdx[U * LCAP];
    __shared__ int slvl[U];
    __shared__ int hist[U];
    __shared__ int changed;
    __shared__ int snl;
    __shared__ float Ms[(U + 1) * 32];    // row U = zeros (dummy target)
    __shared__ float sInv[U];
    __shared__ u16 sOrd[U];
    __shared__ unsigned char sCnt[U];
    __shared__ int sLs[U + 1];
    __shared__ float scf[U];
    int t = threadIdx.x;
    for (int i = t; i < U * LCAP / 2; i += 256) ((unsigned int*)sIdx)[i] = ((const unsigned int*)lessIdx)[i];
    int myCnt = lessCnt[t];
    sCnt[t] = (unsigned char)myCnt;
    sInv[t] = invDeg[t];
    scf[t] = coef[t];
    slvl[t] = 0; hist[t] = 0;
    __syncthreads();
    // Jacobi to level fixpoint (verbatim-verified logic)
    for (int iter = 0; iter < U; ++iter) {
        if (t == 0) changed = 0;
        __syncthreads();
        int nl = 0;
        for (int i = 0; i < myCnt; ++i) nl = max(nl, slvl[sIdx[t * LCAP + i]] + 1);
        if (nl > slvl[t]) { slvl[t] = nl; changed = 1; }
        __syncthreads();
        if (!changed) break;   // uniform
    }
    int L = slvl[t];
    atomicAdd(&hist[L], 1);
    __syncthreads();
    if (t == 0) {
        int acc = 0, lastl = 0;
        for (int l = 0; l < U; ++l) {
            int h = hist[l];
            hist[l] = acc;          // hist becomes start offset
            acc += h;
            if (h > 0) lastl = l;
        }
        snl = lastl + 1;
    }
    __syncthreads();
    sLs[t] = hist[t];               // save starts BEFORE scatter clobbers
    if (t == 0) sLs[U] = U;
    if (t < 32) Ms[U * 32 + t] = 0.f;
    __syncthreads();
    int pos = atomicAdd(&hist[L], 1);
    sOrd[pos] = (u16)t;
    int nlv = snl;
    __syncthreads();
    // level-parallel forward substitution (verbatim-verified logic)
    int g = t >> 5, c = t & 31;
    int col = blockIdx.x * 32 + c;
    for (int lev = 0; lev < nlv; ++lev) {
        int s = sLs[lev], e = sLs[lev + 1];
        for (int base = s + g; base < e; base += 8) {
            int k = sOrd[base];
            int cnt = sCnt[k];
            const u16* ip = &sIdx[k * LCAP];
            float sum = 0.f;
            for (int b = 0; b < cnt; b += 8) {
                u16x8 jv = *(const u16x8*)(ip + b);   // one ds_read_b128
                float v0 = Ms[jv[0] * 32 + c];
                float v1 = Ms[jv[1] * 32 + c];
                float v2 = Ms[jv[2] * 32 + c];
                float v3 = Ms[jv[3] * 32 + c];
                float v4 = Ms[jv[4] * 32 + c];
                float v5 = Ms[jv[5] * 32 + c];
                float v6 = Ms[jv[6] * 32 + c];
                float v7 = Ms[jv[7] * 32 + c];
                sum += ((v0 + v1) + (v2 + v3)) + ((v4 + v5) + (v6 + v7));
            }
            float m = (k == col ? 1.f : 0.f) + sInv[k] * sum;
            Ms[k * 32 + c] = m;
            M2[(size_t)k * U + col] = (bf16_t)m;   // row-major for GEMM2 B-frags
        }
        __syncthreads();   // level boundary
    }
    // bvec partial: bvec[k] += sum_{c in this block} M[k][c]*coef[c]
    // staggered column order -> 2-way max LDS bank aliasing
    float s = 0.f;
    #pragma unroll 8
    for (int j = 0; j < 32; ++j) {
        int cl = (j + (t & 31)) & 31;
        s += Ms[t * 32 + cl] * scf[blockIdx.x * 32 + cl];
    }
    atomicAdd(&bvec[t], s);
}

// ---------------------------------------------------------------------------
// K2: mega-kernel. GEMM1: P' = x * Vb^T (16 K-chunks, register-prefetch
// pipeline, verified structure). Epilogue: P = invDeg o P' (f32, exact) ->
// Ures; GEMM2: y = (P_hi + P_lo)(bf16 split) * M2^T + bvec, 4 c-chunks,
// B-fragments read directly from global M2 (L2-hot, 128 KB); then the merged
// x-substitute write (unchanged). RT=32, 3 blocks/CU.
// ---------------------------------------------------------------------------
#define RT 32
#define BK 64
#define LDX 72      // 64 + 8 bf16 pad: 2-way-max LDS banks
#define URS 257     // Ures row stride (f32)

__global__ __launch_bounds__(256, 3) void k_main(const float* __restrict__ x,
    const short* __restrict__ pmap, const bf16_t* __restrict__ Vb,
    const bf16_t* __restrict__ M2, const float* __restrict__ invDeg,
    const float* __restrict__ bvec, float* __restrict__ out)
{
    __shared__ __align__(16) char smem[42112];  // Xl4608+Vl36864 | Ures32896+PAh4608+PAl4608
    __shared__ float sb[U];
    __shared__ float sd[U];
    __shared__ short spm[NN];
    bf16_t* Xl = (bf16_t*)smem;
    bf16_t* Vl = (bf16_t*)(smem + 4608);
    float* Ures = (float*)smem;
    bf16_t* PAh = (bf16_t*)(smem + 32896);
    bf16_t* PAl = (bf16_t*)(smem + 37504);
    int t = threadIdx.x;
    int w = t >> 6, l = t & 63;
    int m = l & 15, q = l >> 4;
    size_t row0 = (size_t)blockIdx.x * RT;
    sb[t] = bvec[t];
    sd[t] = invDeg[t];
    #pragma unroll
    for (int j = 0; j < 4; ++j) spm[t + 256 * j] = pmap[t + 256 * j];
    f32x4 acc[2][4] = {};
    int uv = t >> 3, du = (t & 7) * 8;

    // register prefetch buffers
    float4 xr[2];
    bf16x8 vr[8];

#define LOADC(DB) do { \
    _Pragma("unroll") \
    for (int ii = 0; ii < 2; ++ii) { \
        int flat = t + ii * 256; \
        int r = flat >> 4, c4 = (flat & 15) * 4; \
        xr[ii] = *(const float4*)(x + (row0 + r) * NN + (DB) + c4); \
    } \
    _Pragma("unroll") \
    for (int i = 0; i < 8; ++i) \
        vr[i] = *(const bf16x8*)(Vb + (size_t)(uv + 32 * i) * NN + (DB) + du); \
} while (0)

    LOADC(0);
    for (int db = 0; db < NN; db += BK) {
        __syncthreads();   // prior compute's LDS reads done (covers sb/spm/sd on iter 0)
        // stage X chunk [32r x 64d] fp32 -> bf16 LDS
        #pragma unroll
        for (int ii = 0; ii < 2; ++ii) {
            int flat = t + ii * 256;
            int r = flat >> 4, c4 = (flat & 15) * 4;
            float4 v = xr[ii];
            bf16x4 hv = { (bf16_t)v.x, (bf16_t)v.y, (bf16_t)v.z, (bf16_t)v.w };
            *(bf16x4*)(&Xl[r * LDX + c4]) = hv;
        }
        // stage V chunk [256u x 64d] bf16
        #pragma unroll
        for (int i = 0; i < 8; ++i)
            *(bf16x8*)(&Vl[(uv + 32 * i) * LDX + du]) = vr[i];
        __syncthreads();   // nothing in flight here -> implicit vmcnt(0) free
        if (db + BK < NN) LOADC(db + BK);   // prefetch flies under compute below
        #pragma unroll
        for (int s = 0; s < 2; ++s) {
            bf16x8 af[2];
            #pragma unroll
            for (int R = 0; R < 2; ++R)
                af[R] = *(bf16x8*)(&Xl[(R * 16 + m) * LDX + s * 32 + q * 8]);
            #pragma unroll
            for (int T = 0; T < 4; ++T) {
                bf16x8 bfr = *(bf16x8*)(&Vl[((w * 4 + T) * 16 + m) * LDX + s * 32 + q * 8]);
                #pragma unroll
                for (int R = 0; R < 2; ++R)
                    acc[R][T] = __builtin_amdgcn_mfma_f32_16x16x32_bf16(af[R], bfr, acc[R][T], 0, 0, 0);
            }
        }
    }
#undef LOADC
    __syncthreads();   // all Vl/Xl reads done before Ures overwrite
    // P = invDeg o P' -> Ures[r][u] f32 (exact scaling; C/D layout row=q*4+i, col=m)
    #pragma unroll
    for (int R = 0; R < 2; ++R) {
        #pragma unroll
        for (int T = 0; T < 4; ++T) {
            int u = (w * 4 + T) * 16 + m;
            float dv = sd[u];
            #pragma unroll
            for (int i = 0; i < 4; ++i)
                Ures[(R * 16 + q * 4 + i) * URS + u] = acc[R][T][i] * dv;
        }
    }
    // GEMM2: y = (P_hi + P_lo) * M2^T  (split-bf16 keeps f32-level precision)
    f32x4 acc2[2][4] = {};
    int r2 = t >> 3, c8 = (t & 7) * 8;
    for (int cc = 0; cc < U; cc += BK) {
        __syncthreads();   // Ures visible (1st) / prev chunk's PA reads done
        #pragma unroll
        for (int j = 0; j < 8; ++j) {
            float p = Ures[r2 * URS + cc + c8 + j];
            bf16_t ph = (bf16_t)p;
            float pl = p - (float)ph;
            PAh[r2 * LDX + c8 + j] = ph;
            PAl[r2 * LDX + c8 + j] = (bf16_t)pl;
        }
        __syncthreads();
        #pragma unroll
        for (int s = 0; s < 2; ++s) {
            bf16x8 ah[2], al[2];
            #pragma unroll
            for (int R = 0; R < 2; ++R) {
                ah[R] = *(bf16x8*)(&PAh[(R * 16 + m) * LDX + s * 32 + q * 8]);
                al[R] = *(bf16x8*)(&PAl[(R * 16 + m) * LDX + s * 32 + q * 8]);
            }
            #pragma unroll
            for (int T = 0; T < 4; ++T) {
                int ub = (w * 4 + T) * 16 + m;
                bf16x8 bfr = *(const bf16x8*)(M2 + (size_t)ub * U + cc + s * 32 + q * 8);
                #pragma unroll
                for (int R = 0; R < 2; ++R) {
                    acc2[R][T] = __builtin_amdgcn_mfma_f32_16x16x32_bf16(ah[R], bfr, acc2[R][T], 0, 0, 0);
                    acc2[R][T] = __builtin_amdgcn_mfma_f32_16x16x32_bf16(al[R], bfr, acc2[R][T], 0, 0, 0);
                }
            }
        }
    }
    __syncthreads();   // PA reads done before Ures overwrite
    // y = acc2 + bvec -> Ures
    #pragma unroll
    for (int R = 0; R < 2; ++R) {
        #pragma unroll
        for (int T = 0; T < 4; ++T) {
            int u = (w * 4 + T) * 16 + m;
            float bb = sb[u];
            #pragma unroll
            for (int i = 0; i < 4; ++i)
                Ures[(R * 16 + q * 4 + i) * URS + u] = acc2[R][T][i] + bb;
        }
    }
    __syncthreads();
    // merged single-pass write: re-read x (L3-warm), substitute unknown cols
    s16x4 pm = *(const s16x4*)(&spm[t * 4]);
    #pragma unroll 4
    for (int i = 0; i < RT; ++i) {
        float4 v = *(const float4*)(x + (row0 + i) * NN + t * 4);
        if (pm[0] >= 0) v.x = Ures[i * URS + pm[0]];
        if (pm[1] >= 0) v.y = Ures[i * URS + pm[1]];
        if (pm[2] >= 0) v.z = Ures[i * URS + pm[2]];
        if (pm[3] >= 0) v.w = Ures[i * URS + pm[3]];
        *(float4*)(out + (row0 + i) * NN + t * 4) = v;
    }
}

// ---------------------------------------------------------------------------
extern "C" void kernel_launch(void* const* d_in, const int* in_sizes, int n_in,
                              void* d_out, int out_size, void* d_ws, size_t ws_size,
                              hipStream_t stream)
{
    const float* x       = (const float*)d_in[0];
    const float* A       = (const float*)d_in[1];
    const int*   unknown = (const int*)d_in[2];
    const float* maskp   = (const float*)d_in[3];
    float* out = (float*)d_out;

    char* ws = (char*)d_ws;
    bf16_t* Vb      = (bf16_t*)(ws + 0);        // 524288 B
    bf16_t* M2      = (bf16_t*)(ws + 524288);   // 131072 B
    float*  invDeg  = (float*)(ws + 655360);    // 1024 B
    float*  coef    = (float*)(ws + 656384);    // 1024 B
    float*  bvec    = (float*)(ws + 657408);    // 1024 B
    int*    lessCnt = (int*)(ws + 658432);      // 1024 B
    u16*    lessIdx = (u16*)(ws + 659456);      // 16384 B
    short*  pmap    = (short*)(ws + 675840);    // 2048 B

    hipLaunchKernelGGL(k_struct, dim3(U), dim3(256), 0, stream,
                       A, unknown, maskp, invDeg, coef, lessCnt, lessIdx, pmap, bvec, Vb);
    hipLaunchKernelGGL(k_mbuild, dim3(8), dim3(256), 0, stream,
                       lessCnt, lessIdx, invDeg, coef, M2, bvec);
    hipLaunchKernelGGL(k_main, dim3(NROWS / RT), dim3(256), 0, stream,
                       x, pmap, Vb, M2, invDeg, bvec, out);
}

// Round 5
// 314.297 us; speedup vs baseline: 1.5097x; 1.0634x over previous
//
#include <hip/hip_runtime.h>

#define U 256       // unknown node count
#define NN 1024     // total nodes
#define NROWS 32768 // B*T rows
#define LCAP 32     // capacity of "less" (earlier-unknown-neighbor) list per node
#define DUMMY 256   // padded index -> zero row of Ms

typedef __bf16 bf16_t;
typedef __bf16 bf16x4 __attribute__((ext_vector_type(4)));
typedef __bf16 bf16x8 __attribute__((ext_vector_type(8)));
typedef float f32x4 __attribute__((ext_vector_type(4)));
typedef unsigned short u16;
typedef unsigned short u16x8 __attribute__((ext_vector_type(8)));
typedef short s16x4 __attribute__((ext_vector_type(4)));

// ---------------------------------------------------------------------------
// K0: per unknown node k (one block each): deg, 1/deg, coef, less-list
// (ushort, DUMMY-padded). Block 0 also builds uflag + pmap + zeroes bvec.
// ---------------------------------------------------------------------------
__global__ __launch_bounds__(256) void k_struct(const float* __restrict__ A,
    const int* __restrict__ unknown, const float* __restrict__ maskp,
    float* __restrict__ invDeg, float* __restrict__ coef,
    int* __restrict__ lessCnt, u16* __restrict__ lessIdx,
    int* __restrict__ uflag, short* __restrict__ pmap, float* __restrict__ bvec)
{
    __shared__ int sunk[U];
    __shared__ float sdeg;
    __shared__ int scnt, sge;
    int t = threadIdx.x, k = blockIdx.x;
    sunk[t] = unknown[t];
    if (t == 0) { sdeg = 0.f; scnt = 0; sge = 0; }
    __syncthreads();
    int uk = sunk[k];
    float dsum = 0.f;
    for (int i = 0; i < NN / 256; ++i) {
        int n = t + 256 * i;
        float a = A[(size_t)uk * NN + n];
        if (a != 0.f) {
            dsum += a;
            int lo = 0, hi = U;
            while (lo < hi) { int mid = (lo + hi) >> 1; if (sunk[mid] < n) lo = mid + 1; else hi = mid; }
            if (lo < U && sunk[lo] == n) {
                if (lo < k) {
                    int id = atomicAdd(&scnt, 1);
                    if (id < LCAP) lessIdx[k * LCAP + id] = (u16)lo;
                } else {
                    atomicAdd(&sge, 1);
                }
            }
        }
    }
    atomicAdd(&sdeg, dsum);
    __syncthreads();
    int c0 = min(scnt, LCAP);
    if (t >= c0 && t < LCAP) lessIdx[k * LCAP + t] = DUMMY;   // pad
    if (t == 0) {
        float inv = 1.f / sdeg;
        invDeg[k] = inv;
        coef[k] = (float)sge * maskp[0] * inv;
        lessCnt[k] = c0;
    }
    if (k == 0) {
        for (int i = 0; i < NN / 256; ++i) { uflag[t + 256 * i] = 0; pmap[t + 256 * i] = -1; }
        bvec[t] = 0.f;                      // accumulated by k_mbuild atomics
        __syncthreads();
        uflag[sunk[t]] = 1;
        pmap[sunk[t]] = (short)t;
    }
}

// ---------------------------------------------------------------------------
// K1: levels computed REDUNDANTLY per block (8 concurrent blocks -- no extra
// kernel, no grid sync) + level-parallel forward substitution for
// M = (I - Ltilde)^-1. Writes MT[col*U + k] = M[k][col] (f32, col-major for
// k_wbuild's coalesced reads) and atomically accumulates bvec = M * coef.
// ---------------------------------------------------------------------------
__global__ __launch_bounds__(256) void k_mbuild(const int* __restrict__ lessCnt,
    const u16* __restrict__ lessIdx, const float* __restrict__ invDeg,
    const float* __restrict__ coef, float* __restrict__ MT, float* __restrict__ bvec)
{
    __shared__ u16 sIdx[U * LCAP];
    __shared__ int slvl[U];
    __shared__ int hist[U];
    __shared__ int changed;
    __shared__ int snl;
    __shared__ float Ms[(U + 1) * 32];    // row U = zeros (dummy target)
    __shared__ float sInv[U];
    __shared__ u16 sOrd[U];
    __shared__ unsigned char sCnt[U];
    __shared__ int sLs[U + 1];
    __shared__ float scf[U];
    int t = threadIdx.x;
    for (int i = t; i < U * LCAP / 2; i += 256) ((unsigned int*)sIdx)[i] = ((const unsigned int*)lessIdx)[i];
    int myCnt = lessCnt[t];
    sCnt[t] = (unsigned char)myCnt;
    sInv[t] = invDeg[t];
    scf[t] = coef[t];
    slvl[t] = 0; hist[t] = 0;
    __syncthreads();
    // Jacobi to level fixpoint
    for (int iter = 0; iter < U; ++iter) {
        if (t == 0) changed = 0;
        __syncthreads();
        int nl = 0;
        for (int i = 0; i < myCnt; ++i) nl = max(nl, slvl[sIdx[t * LCAP + i]] + 1);
        if (nl > slvl[t]) { slvl[t] = nl; changed = 1; }
        __syncthreads();
        if (!changed) break;   // uniform
    }
    int L = slvl[t];
    atomicAdd(&hist[L], 1);
    __syncthreads();
    if (t == 0) {
        int acc = 0, lastl = 0;
        for (int l = 0; l < U; ++l) {
            int h = hist[l];
            hist[l] = acc;          // hist becomes start offset
            acc += h;
            if (h > 0) lastl = l;
        }
        snl = lastl + 1;
    }
    __syncthreads();
    sLs[t] = hist[t];               // save starts BEFORE scatter clobbers
    if (t == 0) sLs[U] = U;
    if (t < 32) Ms[U * 32 + t] = 0.f;
    __syncthreads();
    int pos = atomicAdd(&hist[L], 1);
    sOrd[pos] = (u16)t;
    int nlv = snl;
    __syncthreads();
    // level-parallel forward substitution
    int g = t >> 5, c = t & 31;
    int col = blockIdx.x * 32 + c;
    for (int lev = 0; lev < nlv; ++lev) {
        int s = sLs[lev], e = sLs[lev + 1];
        for (int base = s + g; base < e; base += 8) {
            int k = sOrd[base];
            int cnt = sCnt[k];
            const u16* ip = &sIdx[k * LCAP];
            float sum = 0.f;
            for (int b = 0; b < cnt; b += 8) {
                u16x8 jv = *(const u16x8*)(ip + b);   // one ds_read_b128
                float v0 = Ms[jv[0] * 32 + c];
                float v1 = Ms[jv[1] * 32 + c];
                float v2 = Ms[jv[2] * 32 + c];
                float v3 = Ms[jv[3] * 32 + c];
                float v4 = Ms[jv[4] * 32 + c];
                float v5 = Ms[jv[5] * 32 + c];
                float v6 = Ms[jv[6] * 32 + c];
                float v7 = Ms[jv[7] * 32 + c];
                sum += ((v0 + v1) + (v2 + v3)) + ((v4 + v5) + (v6 + v7));
            }
            float m = (k == col ? 1.f : 0.f) + sInv[k] * sum;
            Ms[k * 32 + c] = m;
            MT[(size_t)col * U + k] = m;   // col-major (M^T) for k_wbuild
        }
        __syncthreads();   // level boundary
    }
    // bvec partial: bvec[k] += sum_{c in this block} M[k][c]*coef[c]
    float s = 0.f;
    #pragma unroll 8
    for (int j = 0; j < 32; ++j) {
        int cl = (j + (t & 31)) & 31;
        s += Ms[t * 32 + cl] * scf[blockIdx.x * 32 + cl];
    }
    atomicAdd(&bvec[t], s);
}

// ---------------------------------------------------------------------------
// K2: W[u][d] (bf16) from A, M (f32 compute, round-2-verified numerics).
// ---------------------------------------------------------------------------
__global__ __launch_bounds__(256) void k_wbuild(const float* __restrict__ A,
    const int* __restrict__ unknown, const float* __restrict__ invDeg,
    const int* __restrict__ uflag, const float* __restrict__ MT,
    bf16_t* __restrict__ Wb)
{
    int t = threadIdx.x, d = blockIdx.x;
    if (uflag[d]) { Wb[(size_t)t * NN + d] = (bf16_t)0.f; return; }  // block-uniform
    __shared__ int nnz;
    __shared__ int cs[64];
    __shared__ float vsv[64];
    if (t == 0) nnz = 0;
    __syncthreads();
    float a = A[(size_t)unknown[t] * NN + d];
    if (a != 0.f) {
        int id = atomicAdd(&nnz, 1);
        if (id < 64) { cs[id] = t; vsv[id] = a * invDeg[t]; }
    }
    __syncthreads();
    int n = min(nnz, 64);
    float s = 0.f;
    for (int i = 0; i < n; ++i)
        s += MT[(size_t)cs[i] * U + t] * vsv[i];   // coalesced over t; zero above diag
    Wb[(size_t)t * NN + d] = (bf16_t)s;
}

// ---------------------------------------------------------------------------
// K3 v4: GEMM out[:,unknown] = x*W^T + b. 512-THREAD blocks at RT=64:
// same grid (512 -> 2 blocks/CU), same 49 KB LDS, but 8 waves/block ->
// 4 waves/SIMD (2x the TLP of the round-2 config) to hide the per-chunk
// vmcnt/barrier stalls. Wave (rg,cg) = (w>>2, w&3) owns rows rg*32+[0,32),
// col-tiles cg*4+[0,4). Register-prefetch pipeline kept. Fragment indexing
// identical to rounds 1-4 (verified). Epilogue: two 32-row halves through
// the Ures overlay, merged single-pass x-substitute write.
// ---------------------------------------------------------------------------
#define RT 64
#define BK 64
#define LDX 72      // 64 + 8 bf16 pad: 2-way-max LDS banks
#define URS 257     // Ures row stride (f32)

__global__ __launch_bounds__(512, 4) void k_main(const float* __restrict__ x,
    const short* __restrict__ pmap, const bf16_t* __restrict__ Wb,
    const float* __restrict__ bvec, float* __restrict__ out)
{
    __shared__ __align__(16) char smem[46080];  // Xl 9216 + Vl 36864; Ures 32896 overlays
    __shared__ float sb[U];
    __shared__ short spm[NN];
    bf16_t* Xl = (bf16_t*)smem;
    bf16_t* Vl = (bf16_t*)(smem + 9216);
    float* Ures = (float*)smem;
    int t = threadIdx.x;
    int w = t >> 6, l = t & 63;
    int m = l & 15, q = l >> 4;
    int rg = w >> 2, cg = w & 3;
    size_t row0 = (size_t)blockIdx.x * RT;
    if (t < U) sb[t] = bvec[t];
    spm[t] = pmap[t];
    spm[t + 512] = pmap[t + 512];
    f32x4 acc[2][4] = {};
    int uv = t >> 3, du = (t & 7) * 8;   // uv 0..63

    // register prefetch buffers
    float4 xr[2];
    bf16x8 vr[4];

#define LOADC(DB) do { \
    _Pragma("unroll") \
    for (int ii = 0; ii < 2; ++ii) { \
        int flat = t + ii * 512; \
        int r = flat >> 4, c4 = (flat & 15) * 4; \
        xr[ii] = *(const float4*)(x + (row0 + r) * NN + (DB) + c4); \
    } \
    _Pragma("unroll") \
    for (int i = 0; i < 4; ++i) \
        vr[i] = *(const bf16x8*)(Wb + (size_t)(uv + 64 * i) * NN + (DB) + du); \
} while (0)

    LOADC(0);
    for (int db = 0; db < NN; db += BK) {
        __syncthreads();   // prior compute's LDS reads done (covers sb/spm on iter 0)
        // stage X chunk [64r x 64d] fp32 -> bf16 LDS
        #pragma unroll
        for (int ii = 0; ii < 2; ++ii) {
            int flat = t + ii * 512;
            int r = flat >> 4, c4 = (flat & 15) * 4;
            float4 v = xr[ii];
            bf16x4 hv = { (bf16_t)v.x, (bf16_t)v.y, (bf16_t)v.z, (bf16_t)v.w };
            *(bf16x4*)(&Xl[r * LDX + c4]) = hv;
        }
        // stage V chunk [256u x 64d] bf16
        #pragma unroll
        for (int i = 0; i < 4; ++i)
            *(bf16x8*)(&Vl[(uv + 64 * i) * LDX + du]) = vr[i];
        __syncthreads();   // nothing in flight here -> implicit vmcnt(0) free
        if (db + BK < NN) LOADC(db + BK);   // prefetch flies under compute below
        #pragma unroll
        for (int s = 0; s < 2; ++s) {
            bf16x8 af[2];
            #pragma unroll
            for (int R = 0; R < 2; ++R)
                af[R] = *(bf16x8*)(&Xl[(rg * 32 + R * 16 + m) * LDX + s * 32 + q * 8]);
            #pragma unroll
            for (int T = 0; T < 4; ++T) {
                bf16x8 bfr = *(bf16x8*)(&Vl[((cg * 4 + T) * 16 + m) * LDX + s * 32 + q * 8]);
                #pragma unroll
                for (int R = 0; R < 2; ++R)
                    acc[R][T] = __builtin_amdgcn_mfma_f32_16x16x32_bf16(af[R], bfr, acc[R][T], 0, 0, 0);
            }
        }
    }
#undef LOADC
    // epilogue: two 32-row halves; waves with rg==h stage acc (+bias) into Ures
    #pragma unroll
    for (int h = 0; h < 2; ++h) {
        __syncthreads();   // all Vl/Xl (or previous half's Ures) reads done
        if (rg == h) {     // wave-uniform branch
            #pragma unroll
            for (int R = 0; R < 2; ++R) {
                #pragma unroll
                for (int T = 0; T < 4; ++T) {
                    int u = (cg * 4 + T) * 16 + m;
                    float bb = sb[u];
                    #pragma unroll
                    for (int i = 0; i < 4; ++i)
                        Ures[(R * 16 + q * 4 + i) * URS + u] = acc[R][T][i] + bb;
                }
            }
        }
        __syncthreads();
        // merged single-pass write: re-read x (L3-warm), substitute unknown cols
        int c4i = t & 255, rh = t >> 8;
        s16x4 pm = *(const s16x4*)(&spm[c4i * 4]);
        #pragma unroll 4
        for (int it = 0; it < 16; ++it) {
            int lr = 2 * it + rh;   // local row 0..31
            float4 v = *(const float4*)(x + (row0 + h * 32 + lr) * NN + c4i * 4);
            if (pm[0] >= 0) v.x = Ures[lr * URS + pm[0]];
            if (pm[1] >= 0) v.y = Ures[lr * URS + pm[1]];
            if (pm[2] >= 0) v.z = Ures[lr * URS + pm[2]];
            if (pm[3] >= 0) v.w = Ures[lr * URS + pm[3]];
            *(float4*)(out + (row0 + h * 32 + lr) * NN + c4i * 4) = v;
        }
    }
}

// ---------------------------------------------------------------------------
extern "C" void kernel_launch(void* const* d_in, const int* in_sizes, int n_in,
                              void* d_out, int out_size, void* d_ws, size_t ws_size,
                              hipStream_t stream)
{
    const float* x       = (const float*)d_in[0];
    const float* A       = (const float*)d_in[1];
    const int*   unknown = (const int*)d_in[2];
    const float* maskp   = (const float*)d_in[3];
    float* out = (float*)d_out;

    char* ws = (char*)d_ws;
    float*  MT      = (float*)(ws + 0);        // 262144 B
    bf16_t* Wb      = (bf16_t*)(ws + 262144);  // 524288 B
    float*  invDeg  = (float*)(ws + 786432);   // 1024 B
    float*  coef    = (float*)(ws + 787456);   // 1024 B
    float*  bvec    = (float*)(ws + 788480);   // 1024 B
    int*    lessCnt = (int*)(ws + 789504);     // 1024 B
    u16*    lessIdx = (u16*)(ws + 790528);     // 16384 B
    int*    uflag   = (int*)(ws + 806912);     // 4096 B
    short*  pmap    = (short*)(ws + 811008);   // 2048 B

    hipLaunchKernelGGL(k_struct, dim3(U), dim3(256), 0, stream,
                       A, unknown, maskp, invDeg, coef, lessCnt, lessIdx, uflag, pmap, bvec);
    hipLaunchKernelGGL(k_mbuild, dim3(8), dim3(256), 0, stream,
                       lessCnt, lessIdx, invDeg, coef, MT, bvec);
    hipLaunchKernelGGL(k_wbuild, dim3(NN), dim3(256), 0, stream,
                       A, unknown, invDeg, uflag, MT, Wb);
    hipLaunchKernelGGL(k_main, dim3(NROWS / RT), dim3(512), 0, stream,
                       x, pmap, Wb, bvec, out);
}